// Round 1
// baseline (2817.815 us; speedup 1.0000x reference)
//
#include <hip/hip_runtime.h>
#include <cstdint>
#include <cstddef>

#define DIM_SOL 4096
#define DIM_CTX 4096
#define DIM_HID 8192
#define NWG 32                    // serial-phase workgroups (4 waves each)
#define KSTEP 6                   // steps per sync round
#define NROUND ((DIM_SOL + KSTEP - 1) / KSTEP)   // 683 (last round: 2 phantom steps)

// Workspace layout (bytes):
//   [0,     32768) : pub slots, 2 banks x 32 slots x 512B (64 u64; word w = {node_w bits | tag32})
//   [32768, 65536) : a0, 8192 floats.  pbuf ALIASES the first 16384 bytes (4096 floats):
//                    safe because WG0/tid0 writes pbuf[6r..] only after the round-r poll
//                    succeeded, which requires every WG to have published round r, which
//                    requires every thread to have already loaded its a0[e] into registers.
//   [65536, +128MB): Wp packed transpose of W[:,4096:] (row i = column 4096+i of W)
// All pub traffic is RELAXED agent-scope atomics; each u64 carries its own tag
// (no fences -> no buffer_wbl2/buffer_inv). Harness poisons ws with 0xAA: tag dword
// 0xAAAAAAAA never equals a valid round tag (1..683). Cross-iteration leftovers are
// also safe: bank0/bank1 end iterations holding tags 683/682, never matching tags 1/2.

__device__ __forceinline__ float sigmoid_precise(float x) {
    return 1.0f / (1.0f + expf(-x));   // decode path: keep identical to passing config
}
__device__ __forceinline__ float hsig(float x) {
    // speculative h path: fast sigmoid (v_exp + v_rcp); ~1ulp -> logit err ~1e-7 rel
    return __builtin_amdgcn_rcpf(1.0f + __expf(-x));
}

// ---------------------------------------------------------------------------
// Prep: a0 GEMV (WGs 0..255) + transpose-pack of W's sol half (WGs 256..2047)
// ---------------------------------------------------------------------------
__global__ __launch_bounds__(256) void ar_prep(
    const float* __restrict__ W, const float* __restrict__ context,
    const float* __restrict__ c, float* __restrict__ a0,
    float* __restrict__ Wp, int packed)
{
    const int wg  = blockIdx.x;
    const int tid = threadIdx.x;

    if (wg < 256) {
        // a0[r] = c[r] + dot(W[r][0:4096], context); one wave per 8-row group.
        const int wave = wg * 4 + (tid >> 6);   // 0..1023
        const int lane = tid & 63;
        const float4* ctx4 = reinterpret_cast<const float4*>(context);
        const int r0 = wave * 8;
        for (int r = r0; r < r0 + 8; ++r) {
            const float4* Wr4 = reinterpret_cast<const float4*>(W + (size_t)r * DIM_HID);
            float acc = 0.f;
#pragma unroll
            for (int j = 0; j < 16; ++j) {
                float4 w4 = Wr4[lane + 64 * j];
                float4 x4 = ctx4[lane + 64 * j];
                acc = fmaf(w4.x, x4.x, acc);
                acc = fmaf(w4.y, x4.y, acc);
                acc = fmaf(w4.z, x4.z, acc);
                acc = fmaf(w4.w, x4.w, acc);
            }
#pragma unroll
            for (int off = 32; off >= 1; off >>= 1) acc += __shfl_xor(acc, off);
            if (lane == 0) a0[r] = c[r] + acc;
        }
    } else if (packed) {
        // Tiled 64x64 transpose: Wp[i][k] = W[k][4096+i]
        __shared__ float tile[64][65];
        const int tx = tid & 63, ty = tid >> 6;   // ty 0..3
        for (int t = wg - 256; t < 64 * 128; t += 1792) {
            const int i0 = (t & 63) * 64;   // sol tile
            const int k0 = (t >> 6) * 64;   // hidden tile
            __syncthreads();
#pragma unroll
            for (int dy = 0; dy < 64; dy += 4) {
                tile[dy + ty][tx] =
                    W[(size_t)(k0 + dy + ty) * DIM_HID + (DIM_CTX + i0 + tx)];
            }
            __syncthreads();
#pragma unroll
            for (int dy = 0; dy < 64; dy += 4) {
                Wp[(size_t)(i0 + dy + ty) * DIM_HID + (k0 + tx)] = tile[tx][dy + ty];
            }
        }
    }
}

// ---------------------------------------------------------------------------
// Serial phase: K=6 speculative steps per all-relaxed global sync round.
// 256 threads/WG (4 waves, 1 hidden elem per thread). 63 tree nodes in heap
// order: node(d,bits) = 2^d-1+bits, bits LSB = earliest step. Per-wave
// reduce-scatter leaves node l on lane l; 4-wave LDS combine; wave0 publishes
// 63 tagged words; each wave polls a disjoint 16-word range over all 32 slots;
// totals exchanged via LDS tot[64]; all threads decode identically.
// ---------------------------------------------------------------------------
__global__ __launch_bounds__(256, 1) void ar_serial(
    const float* __restrict__ V, const float* __restrict__ W,
    const float* __restrict__ b, const float* __restrict__ u,
    const float* a0, const float* __restrict__ Wp,
    unsigned long long* __restrict__ pub,
    float* pbuf, float* __restrict__ out, int packed)
{
    const int g   = blockIdx.x;
    const int tid = threadIdx.x;
    const int wv  = tid >> 6;          // wave 0..3
    const int l   = tid & 63;          // lane
    const int e   = g * 256 + tid;     // this thread's hidden element

    __shared__ float lred[2][4][64];   // ping-pong banks: [bank][wave][node]
    __shared__ float tot[64];          // per-round node totals (barrier-protected)

    float a = a0[e];

    auto loadW = [&](int i) -> float {
        if (packed) return Wp[(size_t)i * DIM_HID + e];
        return W[(size_t)e * DIM_HID + DIM_CTX + i];
    };

    float Vr[KSTEP], Wr[KSTEP], bc[KSTEP], uc[KSTEP];
#pragma unroll
    for (int j = 0; j < KSTEP; ++j) {
        Vr[j] = V[(size_t)j * DIM_HID + e];
        Wr[j] = loadW(j);
        bc[j] = b[j];
        uc[j] = u[j];
    }

    for (int r = 0; r < NROUND; ++r) {
        const unsigned tag = (unsigned)(r + 1);
        unsigned long long* bank = pub + (size_t)(r & 1) * (32 * 64);

        // ---- 32 subset sums of {Wr0..Wr4}, ascending-add order (bit j = step j).
        float xs[32];
        xs[0] = a;
        xs[1] = xs[0] + Wr[0];
        xs[2] = xs[0] + Wr[1];
        xs[3] = xs[1] + Wr[1];
#pragma unroll
        for (int m = 0; m < 4; ++m)  xs[4 + m]  = xs[m] + Wr[2];
#pragma unroll
        for (int m = 0; m < 8; ++m)  xs[8 + m]  = xs[m] + Wr[3];
#pragma unroll
        for (int m = 0; m < 16; ++m) xs[16 + m] = xs[m] + Wr[4];

        float h[32];
#pragma unroll
        for (int m = 0; m < 32; ++m) h[m] = hsig(xs[m]);

        // ---- 63 per-thread node products (heap order), padded to 64.
        float S[64];
        S[0] = Vr[0] * h[0];
#pragma unroll
        for (int m = 0; m < 2; ++m)  S[1 + m]  = Vr[1] * h[m];
#pragma unroll
        for (int m = 0; m < 4; ++m)  S[3 + m]  = Vr[2] * h[m];
#pragma unroll
        for (int m = 0; m < 8; ++m)  S[7 + m]  = Vr[3] * h[m];
#pragma unroll
        for (int m = 0; m < 16; ++m) S[15 + m] = Vr[4] * h[m];
#pragma unroll
        for (int m = 0; m < 32; ++m) S[31 + m] = Vr[5] * h[m];
        S[63] = 0.0f;

        // ---- In-wave reduce-scatter over lane bits 0..5: node n -> lane n.
        {
            const bool hi = l & 1; float o[32];
#pragma unroll
            for (int j = 0; j < 32; ++j) { o[j] = hi ? S[2*j] : S[2*j+1]; S[j] = hi ? S[2*j+1] : S[2*j]; }
#pragma unroll
            for (int j = 0; j < 32; ++j) S[j] += __shfl_xor(o[j], 1);
        }
        {
            const bool hi = l & 2; float o[16];
#pragma unroll
            for (int j = 0; j < 16; ++j) { o[j] = hi ? S[2*j] : S[2*j+1]; S[j] = hi ? S[2*j+1] : S[2*j]; }
#pragma unroll
            for (int j = 0; j < 16; ++j) S[j] += __shfl_xor(o[j], 2);
        }
        {
            const bool hi = l & 4; float o[8];
#pragma unroll
            for (int j = 0; j < 8; ++j) { o[j] = hi ? S[2*j] : S[2*j+1]; S[j] = hi ? S[2*j+1] : S[2*j]; }
#pragma unroll
            for (int j = 0; j < 8; ++j) S[j] += __shfl_xor(o[j], 4);
        }
        {
            const bool hi = l & 8; float o[4];
#pragma unroll
            for (int j = 0; j < 4; ++j) { o[j] = hi ? S[2*j] : S[2*j+1]; S[j] = hi ? S[2*j+1] : S[2*j]; }
#pragma unroll
            for (int j = 0; j < 4; ++j) S[j] += __shfl_xor(o[j], 8);
        }
        {
            const bool hi = l & 16; float o[2];
#pragma unroll
            for (int j = 0; j < 2; ++j) { o[j] = hi ? S[2*j] : S[2*j+1]; S[j] = hi ? S[2*j+1] : S[2*j]; }
#pragma unroll
            for (int j = 0; j < 2; ++j) S[j] += __shfl_xor(o[j], 16);
        }
        {
            const bool hi = l & 32;
            float o = hi ? S[0] : S[1];
            float k = hi ? S[1] : S[0];
            S[0] = k + __shfl_xor(o, 32);   // lane l holds wave-partial of node l
        }

        // ---- Cross-wave combine via LDS (ping-pong banks).
        lred[r & 1][wv][l] = S[0];
        __syncthreads();
        if (wv == 0 && l < 63) {
            const float Twg = ((lred[r & 1][0][l] + lred[r & 1][1][l]) +
                                lred[r & 1][2][l]) + lred[r & 1][3][l];
            unsigned long long v =
                ((unsigned long long)__float_as_uint(Twg) << 32) |
                (unsigned long long)tag;
            __hip_atomic_store(bank + (size_t)g * 64 + l, v,
                               __ATOMIC_RELAXED, __HIP_MEMORY_SCOPE_AGENT);
        }

        // ---- Prefetch next round's rows while the sync is in flight.
        float Vn[KSTEP], Wn[KSTEP], bn[KSTEP], un[KSTEP];
        if (r + 1 < NROUND) {
            const int i1 = KSTEP * (r + 1);
#pragma unroll
            for (int j = 0; j < KSTEP; ++j) {
                int idx = i1 + j;
                if (idx > DIM_SOL - 1) idx = DIM_SOL - 1;   // clamp phantom rows
                Vn[j] = V[(size_t)idx * DIM_HID + e];
                Wn[j] = loadW(idx);
                bn[j] = b[idx];
                un[j] = u[idx];
            }
        }

        // ---- Poll: wave wv covers word wv*16+(l&15) of slots (l>>4)+4k, k<8.
        const int word = wv * 16 + (l & 15);
        {
            unsigned long long q0 = 0, q1 = 0, q2 = 0, q3 = 0,
                               q4 = 0, q5 = 0, q6 = 0, q7 = 0;
            unsigned long long* ms = bank + (size_t)(l >> 4) * 64 + word;
            bool ok = (word == 63);
            for (;;) {
                if (!ok) {
                    q0 = __hip_atomic_load(ms + 0 * 256, __ATOMIC_RELAXED, __HIP_MEMORY_SCOPE_AGENT);
                    q1 = __hip_atomic_load(ms + 1 * 256, __ATOMIC_RELAXED, __HIP_MEMORY_SCOPE_AGENT);
                    q2 = __hip_atomic_load(ms + 2 * 256, __ATOMIC_RELAXED, __HIP_MEMORY_SCOPE_AGENT);
                    q3 = __hip_atomic_load(ms + 3 * 256, __ATOMIC_RELAXED, __HIP_MEMORY_SCOPE_AGENT);
                    q4 = __hip_atomic_load(ms + 4 * 256, __ATOMIC_RELAXED, __HIP_MEMORY_SCOPE_AGENT);
                    q5 = __hip_atomic_load(ms + 5 * 256, __ATOMIC_RELAXED, __HIP_MEMORY_SCOPE_AGENT);
                    q6 = __hip_atomic_load(ms + 6 * 256, __ATOMIC_RELAXED, __HIP_MEMORY_SCOPE_AGENT);
                    q7 = __hip_atomic_load(ms + 7 * 256, __ATOMIC_RELAXED, __HIP_MEMORY_SCOPE_AGENT);
                    ok = ((unsigned)q0 == tag) & ((unsigned)q1 == tag) &
                         ((unsigned)q2 == tag) & ((unsigned)q3 == tag) &
                         ((unsigned)q4 == tag) & ((unsigned)q5 == tag) &
                         ((unsigned)q6 == tag) & ((unsigned)q7 == tag);
                }
                if (__all(ok)) break;
            }
            float G;
            {
                float p0 = __uint_as_float((unsigned)(q0 >> 32));
                float p1 = __uint_as_float((unsigned)(q1 >> 32));
                float p2 = __uint_as_float((unsigned)(q2 >> 32));
                float p3 = __uint_as_float((unsigned)(q3 >> 32));
                float p4 = __uint_as_float((unsigned)(q4 >> 32));
                float p5 = __uint_as_float((unsigned)(q5 >> 32));
                float p6 = __uint_as_float((unsigned)(q6 >> 32));
                float p7 = __uint_as_float((unsigned)(q7 >> 32));
                G = (word == 63) ? 0.0f
                                 : ((((((p0 + p1) + p2) + p3) + p4) + p5) + p6) + p7;
            }
            G += __shfl_xor(G, 16);
            G += __shfl_xor(G, 32);        // lanes l, l^16, l^32, l^48: total of 'word'
            if (l < 16) tot[word] = G;
        }
        __syncthreads();

        // ---- Decode 6 steps (identical uniform computation everywhere).
        float t1[2], t2[4], t3[8], t4[16], t5[32];
        const float T0 = tot[0];
#pragma unroll
        for (int j = 0; j < 2; ++j)  t1[j] = tot[1 + j];
#pragma unroll
        for (int j = 0; j < 4; ++j)  t2[j] = tot[3 + j];
#pragma unroll
        for (int j = 0; j < 8; ++j)  t3[j] = tot[7 + j];
#pragma unroll
        for (int j = 0; j < 16; ++j) t4[j] = tot[15 + j];
#pragma unroll
        for (int j = 0; j < 32; ++j) t5[j] = tot[31 + j];

        const float p0 = sigmoid_precise(bc[0] + T0);
        const bool  s0 = uc[0] < p0;

        const float p1 = sigmoid_precise(bc[1] + (s0 ? t1[1] : t1[0]));
        const bool  s1 = uc[1] < p1;

#pragma unroll
        for (int j = 0; j < 2; ++j)  t2[j] = s0 ? t2[2*j+1] : t2[2*j];
        const float p2 = sigmoid_precise(bc[2] + (s1 ? t2[1] : t2[0]));
        const bool  s2 = uc[2] < p2;

#pragma unroll
        for (int j = 0; j < 4; ++j)  t3[j] = s0 ? t3[2*j+1] : t3[2*j];
#pragma unroll
        for (int j = 0; j < 2; ++j)  t3[j] = s1 ? t3[2*j+1] : t3[2*j];
        const float p3 = sigmoid_precise(bc[3] + (s2 ? t3[1] : t3[0]));
        const bool  s3 = uc[3] < p3;

#pragma unroll
        for (int j = 0; j < 8; ++j)  t4[j] = s0 ? t4[2*j+1] : t4[2*j];
#pragma unroll
        for (int j = 0; j < 4; ++j)  t4[j] = s1 ? t4[2*j+1] : t4[2*j];
#pragma unroll
        for (int j = 0; j < 2; ++j)  t4[j] = s2 ? t4[2*j+1] : t4[2*j];
        const float p4 = sigmoid_precise(bc[4] + (s3 ? t4[1] : t4[0]));
        const bool  s4 = uc[4] < p4;

#pragma unroll
        for (int j = 0; j < 16; ++j) t5[j] = s0 ? t5[2*j+1] : t5[2*j];
#pragma unroll
        for (int j = 0; j < 8; ++j)  t5[j] = s1 ? t5[2*j+1] : t5[2*j];
#pragma unroll
        for (int j = 0; j < 4; ++j)  t5[j] = s2 ? t5[2*j+1] : t5[2*j];
#pragma unroll
        for (int j = 0; j < 2; ++j)  t5[j] = s3 ? t5[2*j+1] : t5[2*j];
        const float p5 = sigmoid_precise(bc[5] + (s4 ? t5[1] : t5[0]));
        const bool  s5 = uc[5] < p5;

        if (g == 0 && tid == 0) {
            const int i0 = KSTEP * r;          // i0+3 <= 4095 always
            out[i0 + 0] = s0 ? 1.f : 0.f;  pbuf[i0 + 0] = p0;
            out[i0 + 1] = s1 ? 1.f : 0.f;  pbuf[i0 + 1] = p1;
            out[i0 + 2] = s2 ? 1.f : 0.f;  pbuf[i0 + 2] = p2;
            out[i0 + 3] = s3 ? 1.f : 0.f;  pbuf[i0 + 3] = p3;
            if (i0 + 4 < DIM_SOL) { out[i0 + 4] = s4 ? 1.f : 0.f; pbuf[i0 + 4] = p4; }
            if (i0 + 5 < DIM_SOL) { out[i0 + 5] = s5 ? 1.f : 0.f; pbuf[i0 + 5] = p5; }
        }

        // ---- Commit a (ascending step order; matches reference exactly).
        // Phantom s4/s5 of the last round only touch 'a' after its final use.
        if (s0) a += Wr[0];
        if (s1) a += Wr[1];
        if (s2) a += Wr[2];
        if (s3) a += Wr[3];
        if (s4) a += Wr[4];
        if (s5) a += Wr[5];

        if (r + 1 < NROUND) {
#pragma unroll
            for (int j = 0; j < KSTEP; ++j) {
                Vr[j] = Vn[j]; Wr[j] = Wn[j]; bc[j] = bn[j]; uc[j] = un[j];
            }
        }
    }
}

// ---------------------------------------------------------------------------
// logp = sum_{i<4094} s_i*log(p_i) + (1-s_i)*log1p(-p_i)
// ---------------------------------------------------------------------------
__global__ __launch_bounds__(256) void ar_logp(
    const float* __restrict__ pbuf, float* __restrict__ out)
{
    __shared__ float red[256];
    const int t = threadIdx.x;
    float acc = 0.f;
    for (int i = t; i < DIM_SOL - 2; i += 256) {
        const float p = pbuf[i];
        const float s = out[i];
        acc += (s > 0.5f) ? logf(p) : log1pf(-p);
    }
    red[t] = acc;
    __syncthreads();
    for (int wdt = 128; wdt >= 1; wdt >>= 1) {
        if (t < wdt) red[t] += red[t + wdt];
        __syncthreads();
    }
    if (t == 0) out[DIM_SOL] = red[0];
}

// ---------------------------------------------------------------------------
extern "C" void kernel_launch(void* const* d_in, const int* in_sizes, int n_in,
                              void* d_out, int out_size, void* d_ws, size_t ws_size,
                              hipStream_t stream)
{
    const float* context = (const float*)d_in[0];
    const float* u       = (const float*)d_in[1];
    const float* W       = (const float*)d_in[2];
    const float* V       = (const float*)d_in[3];
    const float* b       = (const float*)d_in[4];
    const float* c       = (const float*)d_in[5];
    float* out = (float*)d_out;

    char* ws = (char*)d_ws;
    unsigned long long* pub = (unsigned long long*)(ws);   // 32 KB
    float* a0   = (float*)(ws + 32768);                    // 32 KB
    float* pbuf = (float*)(ws + 32768);                    // aliases a0[0..4095] (safe, see top)
    float* Wp   = (float*)(ws + 65536);
    const size_t wp_bytes = (size_t)DIM_SOL * DIM_HID * sizeof(float);
    const int packed = (ws_size >= (size_t)65536 + wp_bytes) ? 1 : 0;

    hipLaunchKernelGGL(ar_prep, dim3(2048), dim3(256), 0, stream,
                       W, context, c, a0, Wp, packed);
    hipLaunchKernelGGL(ar_serial, dim3(NWG), dim3(256), 0, stream,
                       V, W, b, u, a0, Wp, pub, pbuf, out, packed);
    hipLaunchKernelGGL(ar_logp, dim3(1), dim3(256), 0, stream, pbuf, out);
}